// Round 8
// baseline (42.611 us; speedup 1.0000x reference)
//
#include <hip/hip_runtime.h>
#include <hip/hip_bf16.h>

#define DIN  1024
#define DOUT 1024
#define MROWS 8192   // B*S = 4*2048

#define BM 256
#define BN 128
#define BK 64
#define NKT (DIN / BK)   // 16 K-tiles

typedef __attribute__((ext_vector_type(8))) short short8;
typedef __attribute__((ext_vector_type(4))) float f32x4;

__device__ __forceinline__ ushort f2bf(float f) {
    union { float f; unsigned u; } x; x.f = f;
    unsigned u = x.u + 0x7fffu + ((x.u >> 16) & 1u);  // RNE
    return (ushort)(u >> 16);
}

// ---------- pass 1 (fused): X f32->bf16 cvt  +  Wv [K][N] -> WvT [N][K] bf16 ----------
__global__ void prep_kernel(const float* __restrict__ X, ushort* __restrict__ Xb,
                            const float* __restrict__ W, ushort* __restrict__ Wt) {
    __shared__ float tile[32][33];
    const int b = blockIdx.x;
    if (b < 2048) {
        const float4* X4 = (const float4*)X;
        ushort4* O4 = (ushort4*)Xb;
        const int n4 = MROWS * DIN / 4;
        for (int idx = b * 256 + threadIdx.x; idx < n4; idx += 2048 * 256) {
            float4 v = X4[idx];
            ushort4 o;
            o.x = f2bf(v.x); o.y = f2bf(v.y); o.z = f2bf(v.z); o.w = f2bf(v.w);
            O4[idx] = o;
        }
    } else {
        const int t = b - 2048;            // 0..1023
        const int bx = (t & 31) * 32;      // n base
        const int by = (t >> 5) * 32;      // k base
        const int tx = threadIdx.x & 31;
        const int ty = threadIdx.x >> 5;   // 0..7
#pragma unroll
        for (int i = 0; i < 32; i += 8)
            tile[ty + i][tx] = W[(size_t)(by + ty + i) * DOUT + (bx + tx)];
        __syncthreads();
#pragma unroll
        for (int i = 0; i < 32; i += 8)
            Wt[(size_t)(bx + ty + i) * DIN + (by + tx)] = f2bf(tile[tx][ty + i]);
    }
}

// ---------- pass 2: C[M][N] = Xb[M][K] @ WvT[N][K]^T + bias ----------
// R2 geometry + PHASE-AHEAD REGISTER PIPELINE (m201 core): each phase's
// ds_reads fetch the NEXT phase's fragments; MFMA consumes fragments read
// one phase earlier. No lgkm pins / sched_barriers — compiler emits the
// counted lgkmcnt automatically. 2 barriers/tile, counted vmcnt(6)/tile.
__global__ __launch_bounds__(512, 2) void gemm_bias(
    const ushort* __restrict__ Xb,    // [8192][1024] bf16
    const ushort* __restrict__ Wt,    // [1024 n][1024 k] bf16
    const float* __restrict__ bias,   // [1024]
    float* __restrict__ out)          // [8192][1024] f32
{
    __shared__ ushort As[3][BM * BK];   // 3 x 32 KiB
    __shared__ ushort Bs[3][BN * BK];   // 3 x 16 KiB   (144 KiB)

    const int tid  = threadIdx.x;
    const int lane = tid & 63;
    const int wid  = tid >> 6;     // 0..7
    const int wr   = wid >> 1;     // 0..3  (wave M slab, 64 rows)
    const int wc   = wid & 1;      // 0..1  (wave N slab, 64 cols)

    // XCD-aware bijective swizzle: 256 blocks = 8 XCDs x 32 (n fastest).
    const int bid = blockIdx.x;
    const int swz = (bid & 7) * 32 + (bid >> 3);
    const int bm = (swz >> 3) * BM;
    const int bn = (swz & 7) * BN;

    // Stage full K-tile kt into buffer b: A 4 + B 2 gload_lds w16 per thread.
    // LDS dest LINEAR; T2 swizzle via XOR-permuted global source (rule #21).
    auto stage = [&](int b, int kt) {
#pragma unroll
        for (int j = 0; j < 4; ++j) {
            const int c   = j * 512 + tid;      // chunk 0..2047
            const int rl  = c >> 3;             // row 0..255
            const int scc = (c & 7) ^ (rl & 7);
            __builtin_amdgcn_global_load_lds(
                (const __attribute__((address_space(1))) void*)(Xb + (size_t)(bm + rl) * DIN + kt * BK + scc * 8),
                (__attribute__((address_space(3))) void*)(&As[b][(j * 512 + wid * 64) * 8]),
                16, 0, 0);
        }
#pragma unroll
        for (int j = 0; j < 2; ++j) {
            const int c   = j * 512 + tid;      // chunk 0..1023
            const int rl  = c >> 3;             // row 0..127
            const int scc = (c & 7) ^ (rl & 7);
            __builtin_amdgcn_global_load_lds(
                (const __attribute__((address_space(1))) void*)(Wt + (size_t)(bn + rl) * DIN + kt * BK + scc * 8),
                (__attribute__((address_space(3))) void*)(&Bs[b][(j * 512 + wid * 64) * 8]),
                16, 0, 0);
        }
    };

    f32x4 acc[4][4];
#pragma unroll
    for (int i = 0; i < 4; ++i)
#pragma unroll
        for (int j = 0; j < 4; ++j)
            acc[i][j] = (f32x4){0.f, 0.f, 0.f, 0.f};

    const int am  = wr * 64 + (lane & 15);
    const int bnr = wc * 64 + (lane & 15);
    const int g   = lane >> 4;

    // Read the 8 fragments (4 A + 4 B) for k-half ks of buffer buf.
    auto readFrags = [&](short8* fa, short8* fb, int buf, int ks) {
        const int sc = ((ks * 4 + g) ^ (lane & 7)) * 8;
#pragma unroll
        for (int i = 0; i < 4; ++i)
            fa[i] = *(const short8*)(&As[buf][(am + i * 16) * BK + sc]);
#pragma unroll
        for (int j = 0; j < 4; ++j)
            fb[j] = *(const short8*)(&Bs[buf][(bnr + j * 16) * BK + sc]);
    };
    auto mfma16 = [&](const short8* fa, const short8* fb) {
        __builtin_amdgcn_s_setprio(1);
#pragma unroll
        for (int i = 0; i < 4; ++i)
#pragma unroll
            for (int j = 0; j < 4; ++j)
                acc[i][j] = __builtin_amdgcn_mfma_f32_16x16x32_bf16(fa[i], fb[j], acc[i][j], 0, 0, 0);
        __builtin_amdgcn_s_setprio(0);
    };

    short8 xa[4], xb_[4];   // set X: holds (t, ks=0)
    short8 ya[4], yb_[4];   // set Y: holds (t, ks=1)

    // ---- prologue: stage tiles 0,1; wait tile 0; preload X <- (0,0) ----
    stage(0, 0);
    stage(1, 1);
    asm volatile("s_waitcnt vmcnt(6)" ::: "memory");   // tile 0 landed; tile 1 in flight
    __builtin_amdgcn_s_barrier();
    readFrags(xa, xb_, 0, 0);

    // ---- main loop ----
    for (int t = 0; t < NKT; ++t) {
        const int buf = t % 3;
        // phase 0: stage(t+2) | read Y <- (t,1) | MFMA X
        if (t <= NKT - 3) stage((t + 2) % 3, t + 2);
        readFrags(ya, yb_, buf, 1);
        mfma16(xa, xb_);
        if (t <= NKT - 3)      asm volatile("s_waitcnt vmcnt(6)" ::: "memory");
        else if (t == NKT - 2) asm volatile("s_waitcnt vmcnt(0)" ::: "memory");
        if (t < NKT - 1) __builtin_amdgcn_s_barrier();
        // phase 1: read X <- (t+1,0) | MFMA Y
        if (t < NKT - 1) {
            readFrags(xa, xb_, (t + 1) % 3, 0);
            mfma16(ya, yb_);
            __builtin_amdgcn_s_barrier();
        } else {
            mfma16(ya, yb_);
        }
    }

    // ---- epilogue: bias + store. C/D: col = lane&15, row = (lane>>4)*4 + r ----
    const int crow = bm + wr * 64 + (lane >> 4) * 4;
    const int ccol = bn + wc * 64 + (lane & 15);
#pragma unroll
    for (int j = 0; j < 4; ++j) {
        const int col = ccol + j * 16;
        const float bval = bias[col];
#pragma unroll
        for (int i = 0; i < 4; ++i) {
#pragma unroll
            for (int r = 0; r < 4; ++r)
                out[(size_t)(crow + i * 16 + r) * DOUT + col] = acc[i][j][r] + bval;
        }
    }
}

// ---------- fallback (only if workspace too small): naive f32 ----------
__global__ void gemm_naive(const float* __restrict__ X, const float* __restrict__ W,
                           const float* __restrict__ b, float* __restrict__ out) {
    int n = blockIdx.x * blockDim.x + threadIdx.x;
    int m = blockIdx.y;
    float acc = b[n];
    for (int k = 0; k < DIN; ++k)
        acc += X[(size_t)m * DIN + k] * W[(size_t)k * DOUT + n];
    out[(size_t)m * DOUT + n] = acc;
}

extern "C" void kernel_launch(void* const* d_in, const int* in_sizes, int n_in,
                              void* d_out, int out_size, void* d_ws, size_t ws_size,
                              hipStream_t stream) {
    // setup_inputs order: X, Wq, bq, Wk, bk, Wv, bv
    const float* X  = (const float*)d_in[0];
    const float* Wv = (const float*)d_in[5];
    const float* bv = (const float*)d_in[6];
    float* out = (float*)d_out;

    const size_t xb_elems = (size_t)MROWS * DIN;
    const size_t wt_elems = (size_t)DOUT * DIN;
    const size_t needed = (xb_elems + wt_elems) * sizeof(ushort);

    if (ws_size < needed) {
        dim3 g(DOUT / 256, MROWS);
        gemm_naive<<<g, 256, 0, stream>>>(X, Wv, bv, out);
        return;
    }

    ushort* Xb = (ushort*)d_ws;
    ushort* Wt = Xb + xb_elems;

    prep_kernel<<<2048 + 1024, 256, 0, stream>>>(X, Xb, Wv, Wt);
    gemm_bias<<<256, 512, 0, stream>>>(Xb, Wt, bv, out);
}

// Round 9
// 40.378 us; speedup vs baseline: 1.0553x; 1.0553x over previous
//
#include <hip/hip_runtime.h>
#include <hip/hip_bf16.h>

#define DIN  1024
#define DOUT 1024
#define MROWS 8192   // B*S = 4*2048

#define BM 64
#define BN 128
#define BK 32
#define NKT (DIN / BK)   // 32 K-tiles

typedef __attribute__((ext_vector_type(8))) short short8;
typedef __attribute__((ext_vector_type(4))) float f32x4;

__device__ __forceinline__ ushort f2bf(float f) {
    union { float f; unsigned u; } x; x.f = f;
    unsigned u = x.u + 0x7fffu + ((x.u >> 16) & 1u);  // RNE
    return (ushort)(u >> 16);
}

// ---------- pass 1 (fused): X f32->bf16 cvt  +  Wv [K][N] -> WvT [N][K] bf16 ----------
__global__ void prep_kernel(const float* __restrict__ X, ushort* __restrict__ Xb,
                            const float* __restrict__ W, ushort* __restrict__ Wt) {
    __shared__ float tile[32][33];
    const int b = blockIdx.x;
    if (b < 2048) {
        const float4* X4 = (const float4*)X;
        ushort4* O4 = (ushort4*)Xb;
        const int n4 = MROWS * DIN / 4;
        for (int idx = b * 256 + threadIdx.x; idx < n4; idx += 2048 * 256) {
            float4 v = X4[idx];
            ushort4 o;
            o.x = f2bf(v.x); o.y = f2bf(v.y); o.z = f2bf(v.z); o.w = f2bf(v.w);
            O4[idx] = o;
        }
    } else {
        const int t = b - 2048;            // 0..1023
        const int bx = (t & 31) * 32;      // n base
        const int by = (t >> 5) * 32;      // k base
        const int tx = threadIdx.x & 31;
        const int ty = threadIdx.x >> 5;   // 0..7
#pragma unroll
        for (int i = 0; i < 32; i += 8)
            tile[ty + i][tx] = W[(size_t)(by + ty + i) * DOUT + (bx + tx)];
        __syncthreads();
#pragma unroll
        for (int i = 0; i < 32; i += 8)
            Wt[(size_t)(bx + ty + i) * DIN + (by + tx)] = f2bf(tile[tx][ty + i]);
    }
}

// ---------- pass 2: C[M][N] = Xb[M][K] @ WvT[N][K]^T + bias ----------
// Occupancy-first m97 structure: 64x128 tile, BK=32, 4 waves, 24 KiB LDS
// double-buffered -> 4 RESIDENT BLOCKS/CU (16 waves/CU). Cross-block TLP
// hides the per-tile stage drain (m114/m97). Plain __syncthreads per tile;
// no manual waitcnt/setprio/sched_barrier (all measured null here).
__global__ __launch_bounds__(256, 4) void gemm_bias(
    const ushort* __restrict__ Xb,    // [8192][1024] bf16
    const ushort* __restrict__ Wt,    // [1024 n][1024 k] bf16
    const float* __restrict__ bias,   // [1024]
    float* __restrict__ out)          // [8192][1024] f32
{
    __shared__ ushort As[2][BM * BK];   // 2 x 4 KiB
    __shared__ ushort Bs[2][BN * BK];   // 2 x 8 KiB   (24 KiB total)

    const int tid  = threadIdx.x;
    const int lane = tid & 63;
    const int wid  = tid >> 6;     // 0..3
    const int wr   = wid >> 1;     // 0..1  (wave M slab, 32 rows)
    const int wc   = wid & 1;      // 0..1  (wave N slab, 64 cols)
    const int g    = lane >> 4;    // k-group 0..3 (16B slot in 64B row)

    // XCD-aware bijective swizzle: 1024 blocks = 8 XCDs x 128 (n fastest:
    // each XCD walks 16 m-panels x 8 n-tiles; its B panel (2MB) stays L2-hot).
    const int bid = blockIdx.x;
    const int swz = (bid & 7) * 128 + (bid >> 3);
    const int bm = (swz >> 3) * BM;
    const int bn = (swz & 7) * BN;

    // Stage K-tile kt into buffer b. A: 256 chunks (1/thread), B: 512 (2/thread).
    // LDS dest LINEAR (wave-uniform base + lane*16); T2 swizzle via XOR-permuted
    // global source slot (c&3)^(row&3) — rule #21 both-sides involution.
    auto stage = [&](int b, int kt) {
        {
            const int c   = tid;                // 0..255
            const int row = c >> 2;             // 0..63
            const int sl  = (c & 3) ^ (row & 3);
            __builtin_amdgcn_global_load_lds(
                (const __attribute__((address_space(1))) void*)(Xb + (size_t)(bm + row) * DIN + kt * BK + sl * 8),
                (__attribute__((address_space(3))) void*)(&As[b][(wid * 64 + lane) * 8]),
                16, 0, 0);
        }
#pragma unroll
        for (int j = 0; j < 2; ++j) {
            const int c   = j * 256 + tid;      // 0..511
            const int row = c >> 2;             // 0..127
            const int sl  = (c & 3) ^ (row & 3);
            __builtin_amdgcn_global_load_lds(
                (const __attribute__((address_space(1))) void*)(Wt + (size_t)(bn + row) * DIN + kt * BK + sl * 8),
                (__attribute__((address_space(3))) void*)(&Bs[b][(j * 256 + wid * 64 + lane) * 8]),
                16, 0, 0);
        }
    };

    f32x4 acc[2][4];
#pragma unroll
    for (int i = 0; i < 2; ++i)
#pragma unroll
        for (int j = 0; j < 4; ++j)
            acc[i][j] = (f32x4){0.f, 0.f, 0.f, 0.f};

    const int am  = wr * 32 + (lane & 15);
    const int bnr = wc * 64 + (lane & 15);

    // ---- prologue ----
    stage(0, 0);
    __syncthreads();

    // ---- main loop: issue stage(t+1) early, compute tile t (one k-step), sync ----
    for (int t = 0; t < NKT; ++t) {
        const int buf = t & 1;
        if (t < NKT - 1) stage(buf ^ 1, t + 1);
        short8 af[2], bfr[4];
#pragma unroll
        for (int i = 0; i < 2; ++i) {
            const int row = am + i * 16;
            const int sl  = g ^ (row & 3);
            af[i] = *(const short8*)(&As[buf][row * BK + sl * 8]);
        }
#pragma unroll
        for (int j = 0; j < 4; ++j) {
            const int row = bnr + j * 16;
            const int sl  = g ^ (row & 3);
            bfr[j] = *(const short8*)(&Bs[buf][row * BK + sl * 8]);
        }
#pragma unroll
        for (int i = 0; i < 2; ++i)
#pragma unroll
            for (int j = 0; j < 4; ++j)
                acc[i][j] = __builtin_amdgcn_mfma_f32_16x16x32_bf16(af[i], bfr[j], acc[i][j], 0, 0, 0);
        __syncthreads();
    }

    // ---- epilogue: bias + store. C/D: col = lane&15, row = (lane>>4)*4 + r ----
    const int crow = bm + wr * 32 + (lane >> 4) * 4;
    const int ccol = bn + wc * 64 + (lane & 15);
#pragma unroll
    for (int j = 0; j < 4; ++j) {
        const int col = ccol + j * 16;
        const float bval = bias[col];
#pragma unroll
        for (int i = 0; i < 2; ++i) {
#pragma unroll
            for (int r = 0; r < 4; ++r)
                out[(size_t)(crow + i * 16 + r) * DOUT + col] = acc[i][j][r] + bval;
        }
    }
}

// ---------- fallback (only if workspace too small): naive f32 ----------
__global__ void gemm_naive(const float* __restrict__ X, const float* __restrict__ W,
                           const float* __restrict__ b, float* __restrict__ out) {
    int n = blockIdx.x * blockDim.x + threadIdx.x;
    int m = blockIdx.y;
    float acc = b[n];
    for (int k = 0; k < DIN; ++k)
        acc += X[(size_t)m * DIN + k] * W[(size_t)k * DOUT + n];
    out[(size_t)m * DOUT + n] = acc;
}

extern "C" void kernel_launch(void* const* d_in, const int* in_sizes, int n_in,
                              void* d_out, int out_size, void* d_ws, size_t ws_size,
                              hipStream_t stream) {
    // setup_inputs order: X, Wq, bq, Wk, bk, Wv, bv
    const float* X  = (const float*)d_in[0];
    const float* Wv = (const float*)d_in[5];
    const float* bv = (const float*)d_in[6];
    float* out = (float*)d_out;

    const size_t xb_elems = (size_t)MROWS * DIN;
    const size_t wt_elems = (size_t)DOUT * DIN;
    const size_t needed = (xb_elems + wt_elems) * sizeof(ushort);

    if (ws_size < needed) {
        dim3 g(DOUT / 256, MROWS);
        gemm_naive<<<g, 256, 0, stream>>>(X, Wv, bv, out);
        return;
    }

    ushort* Xb = (ushort*)d_ws;
    ushort* Wt = Xb + xb_elems;

    prep_kernel<<<2048 + 1024, 256, 0, stream>>>(X, Xb, Wv, Wt);
    gemm_bias<<<1024, 256, 0, stream>>>(Xb, Wt, bv, out);
}